// Round 2
// baseline (1275.938 us; speedup 1.0000x reference)
//
#include <hip/hip_runtime.h>
#include <cstddef>

#define TT 256
#define HH 128
#define EST 132    // E row stride: b128 reads land 8 dwords on every bank = balanced

__device__ __forceinline__ float rdlane(float v, int l) {
  return __int_as_float(__builtin_amdgcn_readlane(__float_as_int(v), l));
}
__device__ __forceinline__ float fast_sigmoid(float x) {
  const float L2E = 1.4426950408889634f;
  float y = __builtin_amdgcn_exp2f(-x * L2E);
  return __builtin_amdgcn_rcpf(1.0f + y);
}
__device__ __forceinline__ float fast_tanh(float x) {
  const float C2 = 2.8853900817779268f;   // 2*log2(e)
  float y = __builtin_amdgcn_exp2f(x * C2);
  return 1.0f - 2.0f * __builtin_amdgcn_rcpf(1.0f + y);
}

// One workgroup per batch element; 512 threads = 8 waves (2/SIMD).
// Occupancy is LDS-pinned to 1 WG/CU, so 2 waves/SIMD is the ONLY
// achievable occupancy -> amdgpu_waves_per_eu(2,2) licenses the allocator to
// use the full 256 arch-VGPR budget (R1 showed the 4/SIMD 128-reg budget
// forces a 64V+64A split and a net regression).
// R2: per-wave score partials accumulate via ds_add_f32 into a single
// double-buffered 256-float row (srow) -> R-window reduce is ONE b128 read
// per wave instead of 8 reads + 32 adds (kills the redundancy that scaled
// with wave count and dominated the LDS pipe).
__global__ __attribute__((amdgpu_flat_work_group_size(512, 512),
                          amdgpu_waves_per_eu(2, 2)))
void decoder_kernel(const float* __restrict__ x,
                    const float* __restrict__ enc_output,
                    const float* __restrict__ h0,
                    const float* __restrict__ c0,
                    const float* __restrict__ W1,
                    const float* __restrict__ W2,
                    const float* __restrict__ V,
                    const float* __restrict__ Wk,
                    const float* __restrict__ Wr,
                    const float* __restrict__ bias,
                    float* __restrict__ out)
{
  __shared__ float E[TT * EST];      // 135168 B : exp2(C2 * enc_proj)
  __shared__ float zpart[4 * 512];   // 8192 B   : h@Wr k-quarter partials
  __shared__ float srow[2][260];     // 2080 B   : ds_add-accumulated scores
  __shared__ float hbuf[HH];         // 512 B
  // total 145952 B <= 160 KiB

  const int u    = threadIdx.x;
  const int b    = blockIdx.x;
  const int lane = u & 63;
  const int w    = u >> 6;           // wave 0..7 (owns k in [16w,16w+16) for C/D)
  const float C2  = 2.8853900817779268f;
  const float L2E = 1.4426950408889634f;

  // ---------------- P0: enc_proj = enc_output[b] @ W1 -> E (raw) ----------------
  {
    const float* encb = enc_output + (size_t)b * TT * HH;
    const int tsub = u >> 4;
    const int ks   = (u & 15) * 8;
    for (int p = 0; p < 8; ++p) {
      const int tt = p * 32 + tsub;
      float4 a0 = {0.f, 0.f, 0.f, 0.f};
      float4 a1 = {0.f, 0.f, 0.f, 0.f};
      const float4* er4 = (const float4*)(encb + tt * HH);
      for (int j4 = 0; j4 < 32; ++j4) {
        const float4 ev = er4[j4];
        const float* w1p = W1 + (j4 * 4) * HH + ks;
        float4 wa, wb;
        wa = *(const float4*)(w1p + 0 * HH); wb = *(const float4*)(w1p + 0 * HH + 4);
        a0.x += ev.x * wa.x; a0.y += ev.x * wa.y; a0.z += ev.x * wa.z; a0.w += ev.x * wa.w;
        a1.x += ev.x * wb.x; a1.y += ev.x * wb.y; a1.z += ev.x * wb.z; a1.w += ev.x * wb.w;
        wa = *(const float4*)(w1p + 1 * HH); wb = *(const float4*)(w1p + 1 * HH + 4);
        a0.x += ev.y * wa.x; a0.y += ev.y * wa.y; a0.z += ev.y * wa.z; a0.w += ev.y * wa.w;
        a1.x += ev.y * wb.x; a1.y += ev.y * wb.y; a1.z += ev.y * wb.z; a1.w += ev.y * wb.w;
        wa = *(const float4*)(w1p + 2 * HH); wb = *(const float4*)(w1p + 2 * HH + 4);
        a0.x += ev.z * wa.x; a0.y += ev.z * wa.y; a0.z += ev.z * wa.z; a0.w += ev.z * wa.w;
        a1.x += ev.z * wb.x; a1.y += ev.z * wb.y; a1.z += ev.z * wb.z; a1.w += ev.z * wb.w;
        wa = *(const float4*)(w1p + 3 * HH); wb = *(const float4*)(w1p + 3 * HH + 4);
        a0.x += ev.w * wa.x; a0.y += ev.w * wa.y; a0.z += ev.w * wa.z; a0.w += ev.w * wa.w;
        a1.x += ev.w * wb.x; a1.y += ev.w * wb.y; a1.z += ev.w * wb.z; a1.w += ev.w * wb.w;
      }
      *(float4*)(&E[tt * EST + ks])     = a0;
      *(float4*)(&E[tt * EST + ks + 4]) = a1;
    }
  }

  // ---------------- persistent registers ----------------
  // Apre: thread (kq = u>>7, cs = u&127) owns cols 4cs..4cs+3, k in [32kq,+32)
  const int kq = u >> 7;             // wave-uniform (w>>1)
  const int cs = u & 127;
  float4 wr4[32];
  #pragma unroll
  for (int i = 0; i < 32; ++i)
    wr4[i] = *(const float4*)(Wr + (32 * kq + i) * 512 + 4 * cs);
  // Gates: lanes 0..31 of waves 0..3 own unit m = 32w+lane (SIMD-balanced)
  const int m = 32 * (w & 3) + (lane & 31);
  float wkA[4], wkB[4], bbg[4];
  #pragma unroll
  for (int gg = 0; gg < 4; ++gg) {
    wkA[gg] = Wk[gg * HH + m];
    wkB[gg] = Wk[512 + gg * HH + m];
    bbg[gg] = bias[gg * HH + m];
  }
  float c = c0[b * HH + m];
  // x pairs in registers: lane holds t = 64j + lane, j = 0..3
  float2 xr0 = *(const float2*)(x + b * (TT * 2) + 2 * (0 * 64 + lane));
  float2 xr1 = *(const float2*)(x + b * (TT * 2) + 2 * (1 * 64 + lane));
  float2 xr2 = *(const float2*)(x + b * (TT * 2) + 2 * (2 * 64 + lane));
  float2 xr3 = *(const float2*)(x + b * (TT * 2) + 2 * (3 * 64 + lane));
  // Phase C (wave-local): lane -> kk = lane&15, jq = lane>>4
  const int kk = lane & 15;
  const int jq = lane >> 4;
  float w2local[32];                 // W2[32jq+i][16w+kk]
  #pragma unroll
  for (int i = 0; i < 32; ++i)
    w2local[i] = W2[(32 * jq + i) * HH + 16 * w + kk];
  // Phase D: v2 for k = 16w+i via loop-invariant readlane
  const float v2r = -2.0f * V[16 * w + kk];
  float vL[16];
  #pragma unroll
  for (int i = 0; i < 16; ++i) vL[i] = rdlane(v2r, i);
  float ptr0 = 1.0f, ptr1 = 1.0f;
  float svr;
  {
    float v = V[lane] + V[64 + lane];
    #pragma unroll
    for (int o = 1; o < 64; o <<= 1) v += __shfl_xor(v, o, 64);
    svr = v;
  }

  __syncthreads();   // P0 staging visible

  // ---------------- P1: E = exp2(C2 * enc_proj) in place (own chunks) ----------
  {
    float* Er = &E[(u >> 1) * EST + 64 * (u & 1)];
    #pragma unroll
    for (int i = 0; i < 16; ++i) {
      float4 ev = *(const float4*)(Er + 4 * i);
      ev.x = __builtin_amdgcn_exp2f(ev.x * C2);
      ev.y = __builtin_amdgcn_exp2f(ev.y * C2);
      ev.z = __builtin_amdgcn_exp2f(ev.z * C2);
      ev.w = __builtin_amdgcn_exp2f(ev.w * C2);
      *(float4*)(Er + 4 * i) = ev;
    }
  }
  // pre-zero both score rows (D(0) adds into srow[0]; srow[1] zero for D(1))
  if (u < 260) { srow[0][u] = 0.0f; srow[1][u] = 0.0f; }
  // prologue Apre: zpart = h0 @ Wr (h0 from global; hbuf untouched -> no race)
  {
    float hA0 = h0[(size_t)b * HH + 32 * kq + (lane & 31)];
    float4 zac = {0.f, 0.f, 0.f, 0.f};
    #pragma unroll
    for (int i = 0; i < 32; ++i) {
      float hi = rdlane(hA0, i);
      zac.x += hi * wr4[i].x;
      zac.y += hi * wr4[i].y;
      zac.z += hi * wr4[i].z;
      zac.w += hi * wr4[i].w;
    }
    *(float4*)(&zpart[kq * 512 + 4 * cs]) = zac;
  }
  __syncthreads();   // E final + zpart(h0) + srow zero visible

  float* outb = out + (size_t)b * TT * TT;

  // ---------------- step loop: 2 barriers ----------------
  #pragma unroll 1
  for (int step = 0; step < TT; ++step) {
    const int sb = step & 1;         // D adds into srow[sb]; R reads srow[sb^1]
    // ==== R window ====
    if (step > 0) {
      // scores fully reduced in LDS already: one b128 read per wave
      const float4 sc = *(const float4*)(&srow[sb ^ 1][4 * lane]);
      if (w < 4) {
        // ---- argmax path (critical): mx -> ballot -> ptr (regs) -> gates ----
        float m4 = fmaxf(fmaxf(sc.x, sc.y), fmaxf(sc.z, sc.w));
        int ttl = (sc.x == m4) ? 0 : (sc.y == m4) ? 1 : (sc.z == m4) ? 2 : 3;
        float mx = m4;
        #pragma unroll
        for (int o = 1; o < 64; o <<= 1) mx = fmaxf(mx, __shfl_xor(mx, o));
        unsigned long long bal = __ballot(m4 == mx);
        int ls  = __ffsll(bal) - 1;            // first-max lane = lowest t block
        int tc  = 4 * lane + ttl;
        int tts = __builtin_amdgcn_readlane(tc, ls);   // wave-uniform winner t
        int j   = tts >> 6;                    // uniform
        int ll  = tts & 63;                    // uniform
        float2 cand = (j == 0) ? xr0 : (j == 1) ? xr1 : (j == 2) ? xr2 : xr3;
        ptr0 = rdlane(cand.x, ll);
        ptr1 = rdlane(cand.y, ll);
      } else {
        // ---- softmax path (off critical): p -> ws -> out-row store ----
        float s0 = sc.x + svr, s1 = sc.y + svr, s2 = sc.z + svr, s3 = sc.w + svr;
        float p0 = __builtin_amdgcn_exp2f((s0 - 12.0f) * L2E);
        float p1 = __builtin_amdgcn_exp2f((s1 - 12.0f) * L2E);
        float p2 = __builtin_amdgcn_exp2f((s2 - 12.0f) * L2E);
        float p3 = __builtin_amdgcn_exp2f((s3 - 12.0f) * L2E);
        float ws4 = (p0 + p1) + (p2 + p3);
        #pragma unroll
        for (int o = 1; o < 64; o <<= 1) ws4 += __shfl_xor(ws4, o);
        if ((lane >> 4) == (w - 4)) {          // wave 4+i writes t in [64i,64i+64)
          float rs = __builtin_amdgcn_rcpf(ws4);
          float4 po = {p0 * rs, p1 * rs, p2 * rs, p3 * rs};
          *(float4*)(&outb[(size_t)(step - 1) * TT + 4 * lane]) = po;
        }
      }
    }
    if ((lane & 32) == 0 && w < 4) {   // gates: unit m=32w+lane, all 4 gates
      float z0 = bbg[0] + ptr0 * wkA[0] + ptr1 * wkB[0];
      float z1 = bbg[1] + ptr0 * wkA[1] + ptr1 * wkB[1];
      float z2 = bbg[2] + ptr0 * wkA[2] + ptr1 * wkB[2];
      float z3 = bbg[3] + ptr0 * wkA[3] + ptr1 * wkB[3];
      #pragma unroll
      for (int q = 0; q < 4; ++q) {
        z0 += zpart[q * 512 + 0 * HH + m];
        z1 += zpart[q * 512 + 1 * HH + m];
        z2 += zpart[q * 512 + 2 * HH + m];
        z3 += zpart[q * 512 + 3 * HH + m];
      }
      float ig = fast_sigmoid(z0);
      float fg = fast_sigmoid(z1);
      float gg = fast_tanh(z2);
      float og = fast_sigmoid(z3);
      c = fg * c + ig * gg;
      hbuf[m] = og * fast_tanh(c);
    }
    __syncthreads();                 // (W1) h_step visible; srow[sb^1] reads done

    // zero the row R just consumed; next ds_add into it is step+1 (after W3)
    if (w < 4) srow[sb ^ 1][64 * w + lane] = 0.0f;

    // ==== fat window: C (wave-local u_k) + D + Apre ====
    float Uk;
    {
      float cp0 = 0.0f, cp1 = 0.0f;
      const float4* h4 = (const float4*)(hbuf + 32 * jq);
      #pragma unroll
      for (int i4 = 0; i4 < 8; ++i4) {
        float4 hv = h4[i4];
        cp0 += hv.x * w2local[4 * i4 + 0];
        cp1 += hv.y * w2local[4 * i4 + 1];
        cp0 += hv.z * w2local[4 * i4 + 2];
        cp1 += hv.w * w2local[4 * i4 + 3];
      }
      float csum = cp0 + cp1;
      csum += __shfl_xor(csum, 16);
      csum += __shfl_xor(csum, 32);
      Uk = __builtin_amdgcn_exp2f(csum * C2);
    }
    // D: wave w, k in [16w,+16); lane owns t in {lane,64+,128+,192+}
    {
      float uL[16];
      #pragma unroll
      for (int i = 0; i < 16; ++i) uL[i] = rdlane(Uk, i);
      #pragma unroll
      for (int tt = 0; tt < 4; ++tt) {
        const float* Er = &E[(64 * tt + lane) * EST + 16 * w];
        float4 e0 = *(const float4*)(Er + 0);
        float4 e1 = *(const float4*)(Er + 4);
        float4 e2 = *(const float4*)(Er + 8);
        float4 e3 = *(const float4*)(Er + 12);
        float a0 = 0.0f, a1 = 0.0f;
        float t0, t1, n;
        t0 = fmaf(e0.x, uL[ 0], 1.0f); t1 = fmaf(e0.y, uL[ 1], 1.0f);
        n  = fmaf(vL[ 1], t0, vL[ 0] * t1);
        a0 = fmaf(n, __builtin_amdgcn_rcpf(t0 * t1), a0);
        t0 = fmaf(e0.z, uL[ 2], 1.0f); t1 = fmaf(e0.w, uL[ 3], 1.0f);
        n  = fmaf(vL[ 3], t0, vL[ 2] * t1);
        a1 = fmaf(n, __builtin_amdgcn_rcpf(t0 * t1), a1);
        t0 = fmaf(e1.x, uL[ 4], 1.0f); t1 = fmaf(e1.y, uL[ 5], 1.0f);
        n  = fmaf(vL[ 5], t0, vL[ 4] * t1);
        a0 = fmaf(n, __builtin_amdgcn_rcpf(t0 * t1), a0);
        t0 = fmaf(e1.z, uL[ 6], 1.0f); t1 = fmaf(e1.w, uL[ 7], 1.0f);
        n  = fmaf(vL[ 7], t0, vL[ 6] * t1);
        a1 = fmaf(n, __builtin_amdgcn_rcpf(t0 * t1), a1);
        t0 = fmaf(e2.x, uL[ 8], 1.0f); t1 = fmaf(e2.y, uL[ 9], 1.0f);
        n  = fmaf(vL[ 9], t0, vL[ 8] * t1);
        a0 = fmaf(n, __builtin_amdgcn_rcpf(t0 * t1), a0);
        t0 = fmaf(e2.z, uL[10], 1.0f); t1 = fmaf(e2.w, uL[11], 1.0f);
        n  = fmaf(vL[11], t0, vL[10] * t1);
        a1 = fmaf(n, __builtin_amdgcn_rcpf(t0 * t1), a1);
        t0 = fmaf(e3.x, uL[12], 1.0f); t1 = fmaf(e3.y, uL[13], 1.0f);
        n  = fmaf(vL[13], t0, vL[12] * t1);
        a0 = fmaf(n, __builtin_amdgcn_rcpf(t0 * t1), a0);
        t0 = fmaf(e3.z, uL[14], 1.0f); t1 = fmaf(e3.w, uL[15], 1.0f);
        n  = fmaf(vL[15], t0, vL[14] * t1);
        a1 = fmaf(n, __builtin_amdgcn_rcpf(t0 * t1), a1);
        atomicAdd(&srow[sb][64 * tt + lane], a0 + a1);   // ds_add_f32, 2-way banks
      }
    }
    // Apre: zpart = h_step @ Wr; h via broadcast b128 reads (kq wave-uniform)
    {
      const float4* h4 = (const float4*)(hbuf + 32 * kq);
      float4 zac = {0.f, 0.f, 0.f, 0.f};
      #pragma unroll
      for (int i4 = 0; i4 < 8; ++i4) {
        float4 hv = h4[i4];
        zac.x += hv.x * wr4[4 * i4 + 0].x;
        zac.y += hv.x * wr4[4 * i4 + 0].y;
        zac.z += hv.x * wr4[4 * i4 + 0].z;
        zac.w += hv.x * wr4[4 * i4 + 0].w;
        zac.x += hv.y * wr4[4 * i4 + 1].x;
        zac.y += hv.y * wr4[4 * i4 + 1].y;
        zac.z += hv.y * wr4[4 * i4 + 1].z;
        zac.w += hv.y * wr4[4 * i4 + 1].w;
        zac.x += hv.z * wr4[4 * i4 + 2].x;
        zac.y += hv.z * wr4[4 * i4 + 2].y;
        zac.z += hv.z * wr4[4 * i4 + 2].z;
        zac.w += hv.z * wr4[4 * i4 + 2].w;
        zac.x += hv.w * wr4[4 * i4 + 3].x;
        zac.y += hv.w * wr4[4 * i4 + 3].y;
        zac.z += hv.w * wr4[4 * i4 + 3].z;
        zac.w += hv.w * wr4[4 * i4 + 3].w;
      }
      *(float4*)(&zpart[kq * 512 + 4 * cs]) = zac;
    }
    __syncthreads();                 // (W3) srow[sb] + zpart visible
  }

  // ---------------- peel: reduce + store final row (step 255) ----------------
  if (w >= 4) {
    const float4 sc = *(const float4*)(&srow[1][4 * lane]);  // 255&1 == 1
    float s0 = sc.x + svr, s1 = sc.y + svr, s2 = sc.z + svr, s3 = sc.w + svr;
    float p0 = __builtin_amdgcn_exp2f((s0 - 12.0f) * L2E);
    float p1 = __builtin_amdgcn_exp2f((s1 - 12.0f) * L2E);
    float p2 = __builtin_amdgcn_exp2f((s2 - 12.0f) * L2E);
    float p3 = __builtin_amdgcn_exp2f((s3 - 12.0f) * L2E);
    float ws4 = (p0 + p1) + (p2 + p3);
    #pragma unroll
    for (int o = 1; o < 64; o <<= 1) ws4 += __shfl_xor(ws4, o);
    if ((lane >> 4) == (w - 4)) {
      float rs = __builtin_amdgcn_rcpf(ws4);
      float4 po = {p0 * rs, p1 * rs, p2 * rs, p3 * rs};
      *(float4*)(&outb[(size_t)255 * TT + 4 * lane]) = po;
    }
  }
}

extern "C" void kernel_launch(void* const* d_in, const int* in_sizes, int n_in,
                              void* d_out, int out_size, void* d_ws, size_t ws_size,
                              hipStream_t stream) {
  (void)in_sizes; (void)n_in; (void)d_ws; (void)ws_size; (void)out_size;
  const float* x    = (const float*)d_in[0];
  const float* enc  = (const float*)d_in[1];
  const float* h0   = (const float*)d_in[2];
  const float* c0   = (const float*)d_in[3];
  const float* W1   = (const float*)d_in[4];
  const float* W2   = (const float*)d_in[5];
  const float* V    = (const float*)d_in[6];
  const float* Wk   = (const float*)d_in[7];
  const float* Wr   = (const float*)d_in[8];
  const float* bias = (const float*)d_in[9];
  float* out = (float*)d_out;

  decoder_kernel<<<64, 512, 0, stream>>>(x, enc, h0, c0, W1, W2, V, Wk, Wr, bias, out);
}

// Round 4
// 851.000 us; speedup vs baseline: 1.4993x; 1.4993x over previous
//
#include <hip/hip_runtime.h>
#include <cstddef>

#define TT 256
#define HH 128
#define EST 132    // E row stride: b128 reads land 8 dwords on every bank = balanced
#define SCPS 260   // scp row stride: 16B-aligned rows, banks balanced

__device__ __forceinline__ float rdlane(float v, int l) {
  return __int_as_float(__builtin_amdgcn_readlane(__float_as_int(v), l));
}
__device__ __forceinline__ float fast_sigmoid(float x) {
  const float L2E = 1.4426950408889634f;
  float y = __builtin_amdgcn_exp2f(-x * L2E);
  return __builtin_amdgcn_rcpf(1.0f + y);
}
__device__ __forceinline__ float fast_tanh(float x) {
  const float C2 = 2.8853900817779268f;   // 2*log2(e)
  float y = __builtin_amdgcn_exp2f(x * C2);
  return 1.0f - 2.0f * __builtin_amdgcn_rcpf(1.0f + y);
}

// One workgroup per batch element; 512 threads = 8 waves (2/SIMD).
// R4 = R3 folded into a single kernel (R3's two-kernel launch SIGABRT'd the
// harness; all other changes were audited clean, so only that variable is
// removed):
//  (1) softmax deferred OUT of the step loop: svr = sum(V) cancels (softmax
//      and argmax are shift-invariant) and is deleted; waves 4-7 dump the raw
//      reduced score row per step; a TAIL PHASE in the same kernel softmaxes
//      this block's 256 rows (block-private, L2-resident re-read).
//  (2) fat window reordered C -> Apre -> D: Apre's independent 128 fmac hide
//      C's shfl+exp2 latency chain that feeds D's uL.
//  (3) x pairs in LDS (uniform broadcast at use), -8 persistent VGPRs.
// R2 lesson: ds_add_f32 atomics are ~10x a ds_write -- never in the step loop.
__global__ __attribute__((amdgpu_flat_work_group_size(512, 512),
                          amdgpu_waves_per_eu(2, 2)))
void decoder_kernel(const float* __restrict__ x,
                    const float* __restrict__ enc_output,
                    const float* __restrict__ h0,
                    const float* __restrict__ c0,
                    const float* __restrict__ W1,
                    const float* __restrict__ W2,
                    const float* __restrict__ V,
                    const float* __restrict__ Wk,
                    const float* __restrict__ Wr,
                    const float* __restrict__ bias,
                    float* __restrict__ out)
{
  __shared__ float E[TT * EST];      // 135168 B : exp2(C2 * enc_proj)
  __shared__ float zpart[4 * 512];   // 8192 B   : h@Wr k-quarter partials
  __shared__ float scp[8 * SCPS];    // 8320 B   : phase-D partials [kgroup][t]
  __shared__ float hbuf[HH];         // 512 B
  __shared__ float xlds[2 * TT];     // 2048 B   : x pairs (ptr lookup)
  // total 154240 B <= 160 KiB

  const int u    = threadIdx.x;
  const int b    = blockIdx.x;
  const int lane = u & 63;
  const int w    = u >> 6;           // wave 0..7 (owns k in [16w,16w+16) for C/D)
  const float C2  = 2.8853900817779268f;
  const float L2E = 1.4426950408889634f;

  // ---------------- P0: enc_proj = enc_output[b] @ W1 -> E (raw) ----------------
  {
    const float* encb = enc_output + (size_t)b * TT * HH;
    const int tsub = u >> 4;
    const int ks   = (u & 15) * 8;
    for (int p = 0; p < 8; ++p) {
      const int tt = p * 32 + tsub;
      float4 a0 = {0.f, 0.f, 0.f, 0.f};
      float4 a1 = {0.f, 0.f, 0.f, 0.f};
      const float4* er4 = (const float4*)(encb + tt * HH);
      for (int j4 = 0; j4 < 32; ++j4) {
        const float4 ev = er4[j4];
        const float* w1p = W1 + (j4 * 4) * HH + ks;
        float4 wa, wb;
        wa = *(const float4*)(w1p + 0 * HH); wb = *(const float4*)(w1p + 0 * HH + 4);
        a0.x += ev.x * wa.x; a0.y += ev.x * wa.y; a0.z += ev.x * wa.z; a0.w += ev.x * wa.w;
        a1.x += ev.x * wb.x; a1.y += ev.x * wb.y; a1.z += ev.x * wb.z; a1.w += ev.x * wb.w;
        wa = *(const float4*)(w1p + 1 * HH); wb = *(const float4*)(w1p + 1 * HH + 4);
        a0.x += ev.y * wa.x; a0.y += ev.y * wa.y; a0.z += ev.y * wa.z; a0.w += ev.y * wa.w;
        a1.x += ev.y * wb.x; a1.y += ev.y * wb.y; a1.z += ev.y * wb.z; a1.w += ev.y * wb.w;
        wa = *(const float4*)(w1p + 2 * HH); wb = *(const float4*)(w1p + 2 * HH + 4);
        a0.x += ev.z * wa.x; a0.y += ev.z * wa.y; a0.z += ev.z * wa.z; a0.w += ev.z * wa.w;
        a1.x += ev.z * wb.x; a1.y += ev.z * wb.y; a1.z += ev.z * wb.z; a1.w += ev.z * wb.w;
        wa = *(const float4*)(w1p + 3 * HH); wb = *(const float4*)(w1p + 3 * HH + 4);
        a0.x += ev.w * wa.x; a0.y += ev.w * wa.y; a0.z += ev.w * wa.z; a0.w += ev.w * wa.w;
        a1.x += ev.w * wb.x; a1.y += ev.w * wb.y; a1.z += ev.w * wb.z; a1.w += ev.w * wb.w;
      }
      *(float4*)(&E[tt * EST + ks])     = a0;
      *(float4*)(&E[tt * EST + ks + 4]) = a1;
    }
    xlds[u] = x[b * (TT * 2) + u];   // 512 threads cover all 512 floats
  }

  // ---------------- persistent registers ----------------
  // Apre: thread (kq = u>>7, cs = u&127) owns cols 4cs..4cs+3, k in [32kq,+32)
  const int kq = u >> 7;             // wave-uniform (w>>1)
  const int cs = u & 127;
  float4 wr4[32];
  #pragma unroll
  for (int i = 0; i < 32; ++i)
    wr4[i] = *(const float4*)(Wr + (32 * kq + i) * 512 + 4 * cs);
  // Gates: lanes 0..31 of waves 0..3 own unit m = 32w+lane (SIMD-balanced)
  const int m = 32 * (w & 3) + (lane & 31);
  float wkA[4], wkB[4], bbg[4];
  #pragma unroll
  for (int gg = 0; gg < 4; ++gg) {
    wkA[gg] = Wk[gg * HH + m];
    wkB[gg] = Wk[512 + gg * HH + m];
    bbg[gg] = bias[gg * HH + m];
  }
  float c = c0[b * HH + m];
  // Phase C (wave-local): lane -> kk = lane&15, jq = lane>>4
  const int kk = lane & 15;
  const int jq = lane >> 4;
  float w2local[32];                 // W2[32jq+i][16w+kk]
  #pragma unroll
  for (int i = 0; i < 32; ++i)
    w2local[i] = W2[(32 * jq + i) * HH + 16 * w + kk];
  // Phase D: v2 for k = 16w+i via loop-invariant readlane
  const float v2r = -2.0f * V[16 * w + kk];
  float vL[16];
  #pragma unroll
  for (int i = 0; i < 16; ++i) vL[i] = rdlane(v2r, i);
  float ptr0 = 1.0f, ptr1 = 1.0f;

  __syncthreads();   // P0 staging + xlds visible

  // ---------------- P1: E = exp2(C2 * enc_proj) in place (own chunks) ----------
  {
    float* Er = &E[(u >> 1) * EST + 64 * (u & 1)];
    #pragma unroll
    for (int i = 0; i < 16; ++i) {
      float4 ev = *(const float4*)(Er + 4 * i);
      ev.x = __builtin_amdgcn_exp2f(ev.x * C2);
      ev.y = __builtin_amdgcn_exp2f(ev.y * C2);
      ev.z = __builtin_amdgcn_exp2f(ev.z * C2);
      ev.w = __builtin_amdgcn_exp2f(ev.w * C2);
      *(float4*)(Er + 4 * i) = ev;
    }
  }
  // prologue Apre: zpart = h0 @ Wr (h0 from global; hbuf untouched -> no race)
  {
    float hA0 = h0[(size_t)b * HH + 32 * kq + (lane & 31)];
    float4 zac = {0.f, 0.f, 0.f, 0.f};
    #pragma unroll
    for (int i = 0; i < 32; ++i) {
      float hi = rdlane(hA0, i);
      zac.x += hi * wr4[i].x;
      zac.y += hi * wr4[i].y;
      zac.z += hi * wr4[i].z;
      zac.w += hi * wr4[i].w;
    }
    *(float4*)(&zpart[kq * 512 + 4 * cs]) = zac;
  }
  __syncthreads();   // E final + zpart(h0) visible

  float* outb = out + (size_t)b * TT * TT;

  // ---------------- step loop: 2 barriers ----------------
  #pragma unroll 1
  for (int step = 0; step < TT; ++step) {
    // ==== R window ====
    if (step > 0) {
      if (w < 4) {
        // ---- argmax path (critical): reduce -> mx -> ballot -> ptr -> gates ----
        float4 sc = {0.f, 0.f, 0.f, 0.f};
        #pragma unroll
        for (int q = 0; q < 8; ++q) {
          float4 v = *(const float4*)(&scp[q * SCPS + 4 * lane]);
          sc.x += v.x; sc.y += v.y; sc.z += v.z; sc.w += v.w;
        }
        float m4 = fmaxf(fmaxf(sc.x, sc.y), fmaxf(sc.z, sc.w));
        int ttl = (sc.x == m4) ? 0 : (sc.y == m4) ? 1 : (sc.z == m4) ? 2 : 3;
        float mx = m4;
        #pragma unroll
        for (int o = 1; o < 64; o <<= 1) mx = fmaxf(mx, __shfl_xor(mx, o));
        unsigned long long bal = __ballot(m4 == mx);
        int ls  = __ffsll(bal) - 1;            // first-max lane = lowest t block
        int tc  = 4 * lane + ttl;
        int tts = __builtin_amdgcn_readlane(tc, ls);   // wave-uniform winner t
        const float2 pp = *(const float2*)(&xlds[2 * tts]);  // uniform broadcast
        ptr0 = pp.x;
        ptr1 = pp.y;
      } else {
        // ---- score dump (softmax deferred to tail): raw row -> out ----
        const int t = 64 * (w - 4) + lane;
        float s = scp[0 * SCPS + t];
        #pragma unroll
        for (int q = 1; q < 8; ++q) s += scp[q * SCPS + t];
        outb[(size_t)(step - 1) * TT + t] = s;
      }
    }
    if ((lane & 32) == 0 && w < 4) {   // gates: unit m=32w+lane, all 4 gates
      float z0 = bbg[0] + ptr0 * wkA[0] + ptr1 * wkB[0];
      float z1 = bbg[1] + ptr0 * wkA[1] + ptr1 * wkB[1];
      float z2 = bbg[2] + ptr0 * wkA[2] + ptr1 * wkB[2];
      float z3 = bbg[3] + ptr0 * wkA[3] + ptr1 * wkB[3];
      #pragma unroll
      for (int q = 0; q < 4; ++q) {
        z0 += zpart[q * 512 + 0 * HH + m];
        z1 += zpart[q * 512 + 1 * HH + m];
        z2 += zpart[q * 512 + 2 * HH + m];
        z3 += zpart[q * 512 + 3 * HH + m];
      }
      float ig = fast_sigmoid(z0);
      float fg = fast_sigmoid(z1);
      float gg = fast_tanh(z2);
      float og = fast_sigmoid(z3);
      c = fg * c + ig * gg;
      hbuf[m] = og * fast_tanh(c);
    }
    __syncthreads();                 // (W1) h_step visible

    // ==== fat window: C (u_k chain) -> Apre (independent, hides C latency) -> D ====
    float Uk;
    {
      float cp0 = 0.0f, cp1 = 0.0f;
      const float4* h4 = (const float4*)(hbuf + 32 * jq);
      #pragma unroll
      for (int i4 = 0; i4 < 8; ++i4) {
        float4 hv = h4[i4];
        cp0 += hv.x * w2local[4 * i4 + 0];
        cp1 += hv.y * w2local[4 * i4 + 1];
        cp0 += hv.z * w2local[4 * i4 + 2];
        cp1 += hv.w * w2local[4 * i4 + 3];
      }
      float csum = cp0 + cp1;
      csum += __shfl_xor(csum, 16);
      csum += __shfl_xor(csum, 32);
      Uk = __builtin_amdgcn_exp2f(csum * C2);
    }
    // Apre: zpart = h_step @ Wr; h via broadcast b128 reads (kq wave-uniform)
    {
      const float4* h4 = (const float4*)(hbuf + 32 * kq);
      float4 zac = {0.f, 0.f, 0.f, 0.f};
      #pragma unroll
      for (int i4 = 0; i4 < 8; ++i4) {
        float4 hv = h4[i4];
        zac.x += hv.x * wr4[4 * i4 + 0].x;
        zac.y += hv.x * wr4[4 * i4 + 0].y;
        zac.z += hv.x * wr4[4 * i4 + 0].z;
        zac.w += hv.x * wr4[4 * i4 + 0].w;
        zac.x += hv.y * wr4[4 * i4 + 1].x;
        zac.y += hv.y * wr4[4 * i4 + 1].y;
        zac.z += hv.y * wr4[4 * i4 + 1].z;
        zac.w += hv.y * wr4[4 * i4 + 1].w;
        zac.x += hv.z * wr4[4 * i4 + 2].x;
        zac.y += hv.z * wr4[4 * i4 + 2].y;
        zac.z += hv.z * wr4[4 * i4 + 2].z;
        zac.w += hv.z * wr4[4 * i4 + 2].w;
        zac.x += hv.w * wr4[4 * i4 + 3].x;
        zac.y += hv.w * wr4[4 * i4 + 3].y;
        zac.z += hv.w * wr4[4 * i4 + 3].z;
        zac.w += hv.w * wr4[4 * i4 + 3].w;
      }
      *(float4*)(&zpart[kq * 512 + 4 * cs]) = zac;
    }
    // D: wave w, k in [16w,+16); lane owns t in {lane,64+,128+,192+}
    {
      float uL[16];
      #pragma unroll
      for (int i = 0; i < 16; ++i) uL[i] = rdlane(Uk, i);
      #pragma unroll
      for (int tt = 0; tt < 4; ++tt) {
        const float* Er = &E[(64 * tt + lane) * EST + 16 * w];
        float4 e0 = *(const float4*)(Er + 0);
        float4 e1 = *(const float4*)(Er + 4);
        float4 e2 = *(const float4*)(Er + 8);
        float4 e3 = *(const float4*)(Er + 12);
        float a0 = 0.0f, a1 = 0.0f;
        float t0, t1, n;
        t0 = fmaf(e0.x, uL[ 0], 1.0f); t1 = fmaf(e0.y, uL[ 1], 1.0f);
        n  = fmaf(vL[ 1], t0, vL[ 0] * t1);
        a0 = fmaf(n, __builtin_amdgcn_rcpf(t0 * t1), a0);
        t0 = fmaf(e0.z, uL[ 2], 1.0f); t1 = fmaf(e0.w, uL[ 3], 1.0f);
        n  = fmaf(vL[ 3], t0, vL[ 2] * t1);
        a1 = fmaf(n, __builtin_amdgcn_rcpf(t0 * t1), a1);
        t0 = fmaf(e1.x, uL[ 4], 1.0f); t1 = fmaf(e1.y, uL[ 5], 1.0f);
        n  = fmaf(vL[ 5], t0, vL[ 4] * t1);
        a0 = fmaf(n, __builtin_amdgcn_rcpf(t0 * t1), a0);
        t0 = fmaf(e1.z, uL[ 6], 1.0f); t1 = fmaf(e1.w, uL[ 7], 1.0f);
        n  = fmaf(vL[ 7], t0, vL[ 6] * t1);
        a1 = fmaf(n, __builtin_amdgcn_rcpf(t0 * t1), a1);
        t0 = fmaf(e2.x, uL[ 8], 1.0f); t1 = fmaf(e2.y, uL[ 9], 1.0f);
        n  = fmaf(vL[ 9], t0, vL[ 8] * t1);
        a0 = fmaf(n, __builtin_amdgcn_rcpf(t0 * t1), a0);
        t0 = fmaf(e2.z, uL[10], 1.0f); t1 = fmaf(e2.w, uL[11], 1.0f);
        n  = fmaf(vL[11], t0, vL[10] * t1);
        a1 = fmaf(n, __builtin_amdgcn_rcpf(t0 * t1), a1);
        t0 = fmaf(e3.x, uL[12], 1.0f); t1 = fmaf(e3.y, uL[13], 1.0f);
        n  = fmaf(vL[13], t0, vL[12] * t1);
        a0 = fmaf(n, __builtin_amdgcn_rcpf(t0 * t1), a0);
        t0 = fmaf(e3.z, uL[14], 1.0f); t1 = fmaf(e3.w, uL[15], 1.0f);
        n  = fmaf(vL[15], t0, vL[14] * t1);
        a1 = fmaf(n, __builtin_amdgcn_rcpf(t0 * t1), a1);
        scp[w * SCPS + 64 * tt + lane] = a0 + a1;
      }
    }
    __syncthreads();                 // (W3) scp + zpart visible
  }

  // ---------------- peel: dump final raw score row (step 255) ----------------
  if (w >= 4) {
    const int t = 64 * (w - 4) + lane;
    float s = scp[0 * SCPS + t];
    #pragma unroll
    for (int q = 1; q < 8; ++q) s += scp[q * SCPS + t];
    outb[(size_t)255 * TT + t] = s;
  }
  __syncthreads();   // all raw rows globally written & visible block-wide

  // ---------------- tail: softmax this block's 256 rows in place ----------------
  // Shift-invariance: raw scores (svr omitted) give identical probabilities.
  // Rows are block-private and L2-resident (256 KB/block, 2 MB/XCD).
  {
    #pragma unroll 2
    for (int i = 0; i < 32; ++i) {
      float* rp = outb + (size_t)(32 * w + i) * TT;
      float4 v = *(const float4*)(rp + 4 * lane);
      float mx = fmaxf(fmaxf(v.x, v.y), fmaxf(v.z, v.w));
      #pragma unroll
      for (int o = 1; o < 64; o <<= 1) mx = fmaxf(mx, __shfl_xor(mx, o));
      float p0 = __builtin_amdgcn_exp2f((v.x - mx) * L2E);
      float p1 = __builtin_amdgcn_exp2f((v.y - mx) * L2E);
      float p2 = __builtin_amdgcn_exp2f((v.z - mx) * L2E);
      float p3 = __builtin_amdgcn_exp2f((v.w - mx) * L2E);
      float ws = (p0 + p1) + (p2 + p3);
      #pragma unroll
      for (int o = 1; o < 64; o <<= 1) ws += __shfl_xor(ws, o);
      float rs = __builtin_amdgcn_rcpf(ws);
      float4 po = {p0 * rs, p1 * rs, p2 * rs, p3 * rs};
      *(float4*)(rp + 4 * lane) = po;
    }
  }
}

extern "C" void kernel_launch(void* const* d_in, const int* in_sizes, int n_in,
                              void* d_out, int out_size, void* d_ws, size_t ws_size,
                              hipStream_t stream) {
  (void)in_sizes; (void)n_in; (void)d_ws; (void)ws_size; (void)out_size;
  const float* x    = (const float*)d_in[0];
  const float* enc  = (const float*)d_in[1];
  const float* h0   = (const float*)d_in[2];
  const float* c0   = (const float*)d_in[3];
  const float* W1   = (const float*)d_in[4];
  const float* W2   = (const float*)d_in[5];
  const float* V    = (const float*)d_in[6];
  const float* Wk   = (const float*)d_in[7];
  const float* Wr   = (const float*)d_in[8];
  const float* bias = (const float*)d_in[9];
  float* out = (float*)d_out;

  decoder_kernel<<<64, 512, 0, stream>>>(x, enc, h0, c0, W1, W2, V, Wk, Wr, bias, out);
}